// Round 20
// baseline (109.163 us; speedup 1.0000x reference)
//
#include <hip/hip_runtime.h>
#include <hip/hip_bf16.h>

// FirUpsample R19 = R18 (81.6us) + A-side port fixes:
//  (a) COALESCED w-gather: flat-f4 units (lane-consecutive 16B loads, ~16
//      lines/instr vs 64). Writes via incremental kq-walk: per-unit base +
//      (+5136 | wrap-delta) selected by precomputed 2-bit wrap position.
//      KQ_PLANE padded to 5136B so kq planes spread write banks (+4 words).
//  (b) As slot-ROTATION swizzle: ic-half h stored at physical half
//      h ^ ((oc>>3)&1) (closed in the 64B row). Fixes the period-8 bank
//      collision (lanes l, l+8 same bank) that made every A b128 read ~4-way
//      through R17/R18. Read side: aoff includes b*32, h-step = +/-32.
// xs layout untouched (B-read 4-way conflicts remain -- isolated next).
// Math (verified R5-R18, absmax 0.015625): h = dilated conv3x3 as 4 parity-
// plane GEMMs (10.3 G MAC); separable 4-tap FIR epilogue from LDS.

typedef short bf16x8 __attribute__((ext_vector_type(8)));
typedef short short4v __attribute__((ext_vector_type(4)));
typedef float f32x16 __attribute__((ext_vector_type(16)));
typedef float f32x4v __attribute__((ext_vector_type(4)));

static __device__ __forceinline__ short f2bf(float f) {
  __hip_bfloat16 h = __float2bfloat16(f);
  union { __hip_bfloat16 h; short s; } u; u.h = h;
  return u.s;
}
static __device__ __forceinline__ float bf2f(short s) {
  union { unsigned u; float f; } v; v.u = ((unsigned)(unsigned short)s) << 16;
  return v.f;
}

#define KQ_PLANE 5136     // 64 oc * 80 B + 16 B pad (kq bank spread: +4 words)
#define AS_SZ 46224       // 9 * KQ_PLANE
#define AB_OFF 2560       // +32 oc rows
#define XS_BASE 92448     // 2*AS_SZ
#define XS_SZ 14400       // one xs buffer: [180 cells][80 B]
#define XS_STRIDE 80

__global__ __launch_bounds__(512, 2)
void fir_up_v19(const float* __restrict__ x, const float* __restrict__ w,
                float* __restrict__ out) {
  __shared__ __align__(16) char smem[121248];

  const int bid = blockIdx.x;
  const int wg = (bid & 7) * 64 + (bid >> 3);
  const int octile = wg >> 7;        // 0..3 (64 oc each)
  const int n = (wg >> 5) & 3;
  const int sp = wg & 31;
  const int atile = sp >> 2;
  const int btile = sp & 3;
  const int A0 = atile * 8, B0 = btile * 16;

  const int tid = threadIdx.x;
  const int wid = tid >> 6;
  const int lane = tid & 63;
  const int l31 = lane & 31, q = lane >> 5;

  // ---- plane geometry + plane-grouped partition (R17/R18-verified) ----
  const int COLSt[4]  = {17, 18, 17, 18};
  const int CELLSt[4] = {153, 162, 170, 180};
  const int NKt[4]    = {4, 2, 2, 1};
  const int KQt[4][4] = {{0,2,6,8},{1,7,7,7},{3,5,5,5},{4,4,4,4}};
  const int DYt[4][4] = {{0,0,1,1},{0,1,1,1},{0,0,0,0},{0,0,0,0}};
  const int DXt[4][4] = {{0,1,0,1},{0,0,0,0},{0,1,1,1},{0,0,0,0}};
  // seg0: w0 p0{0,1} w1 p0{2,3} w2 p0{4} w3 p1{0,1,2} w4 p1{3,4,5}
  //       w5 p2{0,1,2} w6 p2{3,4,5} w7 p3{0,1,2}
  // seg1: w0 += p3{3} -> acc[2]; w2 += p3{4,5} -> acc[1],acc[2]
  const int SEG0P[8]   = {0,0,0,1,1,2,2,3};
  const int SEG0FGB[8] = {0,2,4,0,3,0,3,0};
  const int SEG0NFG[8] = {2,2,1,3,3,3,3,3};

  const int p0w = SEG0P[wid];
  const int nk0 = NKt[p0w];
  const int nfg0 = SEG0NFG[wid];
  // A-read offsets with slot rotation: physical half = h ^ ((oc>>3)&1)
  const int bA = (l31 >> 3) & 1;
  const int hstepA = 32 - 64 * bA;     // +32 or -32
  int aoff0[4];
#pragma unroll
  for (int s = 0; s < 4; ++s)
    aoff0[s] = KQt[p0w][s] * KQ_PLANE + l31 * 80 + bA * 32 + q * 16;
  int boff0[3][4], valid0[3], hbase0[3];
#pragma unroll
  for (int fg = 0; fg < 3; ++fg) {
    const int cellraw = (SEG0FGB[wid] + fg) * 32 + l31;
    const int valid = cellraw < CELLSt[p0w];
    const int cell = valid ? cellraw : 0;
    const int cols = COLSt[p0w];
    const int r = cell / cols;
    const int c = cell - r * cols;
    valid0[fg] = valid;
    hbase0[fg] = p0w * 6400 + r * 20 + c;
#pragma unroll
    for (int s = 0; s < 4; ++s) {
      const int bc = (r + DYt[p0w][s]) * 18 + (c + DXt[p0w][s]);
      boff0[fg][s] = bc * XS_STRIDE + q * 16;
    }
  }
  const int aoff1 = 4 * KQ_PLANE + l31 * 80 + bA * 32 + q * 16;
  int boffW0, hbaseW0;
  {
    const int cell = 96 + l31;
    const int r = cell / 18, c = cell - r * 18;
    hbaseW0 = 3 * 6400 + r * 20 + c;
    boffW0 = cell * XS_STRIDE + q * 16;
  }
  int boff1[2], valid1[2], hbase1[2];
#pragma unroll
  for (int j = 0; j < 2; ++j) {
    const int cellraw = (4 + j) * 32 + l31;
    const int valid = cellraw < 180;
    const int cell = valid ? cellraw : 0;
    const int r = cell / 18, c = cell - r * 18;
    valid1[j] = valid;
    hbase1[j] = 3 * 6400 + r * 20 + c;
    boff1[j] = cell * XS_STRIDE + q * 16;
  }

  f32x16 acc[3][2];
#pragma unroll
  for (int fg = 0; fg < 3; ++fg)
#pragma unroll
    for (int mf = 0; mf < 2; ++mf)
#pragma unroll
      for (int e = 0; e < 16; ++e) acc[fg][mf][e] = 0.f;

  // ---- A-stage precompute: 9 flat-f4 units (lane-consecutive, chunk-inv) ----
  // unit k: F4 = tid + 512k in [0,4608); oc = F4/72; 4 floats = (ic,kq..kq+3)
  const char* wub = (const char*)(w + (size_t)(octile * 64) * 2304);
  int goffB[9], woff0[9], wdelta[9];
  unsigned wpack = 0;
#pragma unroll
  for (int k = 0; k < 9; ++k) {
    const int F4 = tid + (k << 9);
    const int oc = F4 / 72;
    const int remf = (F4 - oc * 72) * 4;
    const int ic = remf / 9;
    const int kq = remf - ic * 9;
    goffB[k] = F4 * 16 + oc * 8064;          // = oc*9216 + rem4*16
    const int bx = ((oc >> 3) & 1) << 4;     // slot rotation bit for this row
    woff0[k] = kq * KQ_PLANE + oc * 80 + ((ic ^ bx) * 2);
    int wp = 8 - kq; if (wp > 3) wp = 3;     // e-transition where kq wraps (3=none)
    wpack |= (unsigned)wp << (2 * k);
    wdelta[k] = (((ic + 1) ^ bx) - (ic ^ bx)) * 2 - 8 * KQ_PLANE;
  }

  // ---- x-stage decode (verbatim R18) ----
  int uic_[4], urow_[4], uf4g_[4], ugh_[4], ugw0_[4], uwb0_[4];
  bool uact_[4], urowok_[4], ual_[4], uint_[4];
#pragma unroll
  for (int t = 0; t < 4; ++t) {
    const int u = tid + t * 512;
    uact_[t] = u < 1920;
    const int uu = uact_[t] ? u : 0;
    uic_[t] = uu / 60;
    const int rem = uu - uic_[t] * 60;
    urow_[t] = rem / 6;
    uf4g_[t] = rem - urow_[t] * 6;
    ugh_[t] = A0 - 1 + urow_[t];
    urowok_[t] = (ugh_[t] >= 0) & (ugh_[t] < 64);
    ugw0_[t] = B0 - 4 + 4 * uf4g_[t];
    ual_[t] = (ugw0_[t] >= 0) & (ugw0_[t] <= 60);
    uint_[t] = (uf4g_[t] >= 1) & (uf4g_[t] <= 4);
    uwb0_[t] = (urow_[t] * 18 + (4 * uf4g_[t] - 3)) * XS_STRIDE + uic_[t] * 2;
  }

  // ---- prologue: stage chunk 0 into buffers 0 ----
  {
    char* xsw = smem + XS_BASE;
#pragma unroll
    for (int t = 0; t < 4; ++t) {
      if (uact_[t]) {
        float v[4] = {0.f, 0.f, 0.f, 0.f};
        if (urowok_[t]) {
          const float* base = x + (((size_t)(n * 256 + uic_[t])) * 64 + ugh_[t]) * 64;
          if (ual_[t]) {
            const f32x4v fv = *(const f32x4v*)(base + ugw0_[t]);
#pragma unroll
            for (int e = 0; e < 4; ++e) v[e] = fv[e];
          } else {
#pragma unroll
            for (int e = 0; e < 4; ++e) {
              const int gw = ugw0_[t] + e;
              v[e] = (gw >= 0 && gw < 64) ? base[gw] : 0.f;
            }
          }
        }
        if (uint_[t]) {
#pragma unroll
          for (int e = 0; e < 4; ++e)
            *(short*)(xsw + uwb0_[t] + e * XS_STRIDE) = f2bf(v[e]);
        } else {
#pragma unroll
          for (int e = 0; e < 4; ++e) {
            const int ww = 4 * uf4g_[t] + e - 3;
            if (ww >= 0 && ww < 18)
              *(short*)(xsw + (urow_[t] * 18 + ww) * XS_STRIDE + uic_[t] * 2) = f2bf(v[e]);
          }
        }
      }
    }
#pragma unroll
    for (int k = 0; k < 9; ++k) {
      const f32x4v wv0 = *(const f32x4v*)(wub + goffB[k]);
      int a = woff0[k];
      const int wp = (int)((wpack >> (2 * k)) & 3u);
#pragma unroll
      for (int e = 0; e < 4; ++e) {
        *(short*)(smem + a) = f2bf(wv0[e]);
        a += (e == wp) ? wdelta[k] : KQ_PLANE;
      }
    }
  }
  __syncthreads();

  // ---------------- K-loop: 8 chunks of 32 ic, ONE barrier each ----------------
  for (int cc = 0; cc < 8; ++cc) {
    char* Asr = smem + (cc & 1) * AS_SZ;
    char* xsr = smem + XS_BASE + (cc & 1) * XS_SZ;
    char* Asw = smem + ((cc + 1) & 1) * AS_SZ;
    char* xsw = smem + XS_BASE + ((cc + 1) & 1) * XS_SZ;
    const bool have = cc < 7;

    // issue x loads for chunk cc+1 (latency hides under MFMA)
    float xv[4][4];
#pragma unroll
    for (int t = 0; t < 4; ++t) {
#pragma unroll
      for (int e = 0; e < 4; ++e) xv[t][e] = 0.f;
      if (have && uact_[t] && urowok_[t]) {
        const float* base =
            x + (((size_t)(n * 256 + (cc + 1) * 32 + uic_[t])) * 64 + ugh_[t]) * 64;
        if (ual_[t]) {
          const f32x4v fv = *(const f32x4v*)(base + ugw0_[t]);
#pragma unroll
          for (int e = 0; e < 4; ++e) xv[t][e] = fv[e];
        } else {
#pragma unroll
          for (int e = 0; e < 4; ++e) {
            const int gw = ugw0_[t] + e;
            xv[t][e] = (gw >= 0 && gw < 64) ? base[gw] : 0.f;
          }
        }
      }
    }
    // issue w loads for chunk cc+1 (lane-consecutive, coalesced)
    f32x4v wv[9];
#pragma unroll
    for (int k = 0; k < 9; ++k) {
      if (have) wv[k] = *(const f32x4v*)(wub + goffB[k] + (cc + 1) * 1152);
    }

    // MFMA on chunk cc: plane-grouped, 2 ic-halves per kq, prioritized
    __builtin_amdgcn_s_setprio(1);
#pragma unroll
    for (int s = 0; s < 4; ++s) {
      if (s < nk0) {
#pragma unroll
        for (int h = 0; h < 2; ++h) {
          const int ah = aoff0[s] + (h ? hstepA : 0);
          const bf16x8 Aa = *(const bf16x8*)(Asr + ah);
          const bf16x8 Ab = *(const bf16x8*)(Asr + ah + AB_OFF);
#pragma unroll
          for (int fg = 0; fg < 3; ++fg) {
            if (fg < nfg0) {
              const bf16x8 B = *(const bf16x8*)(xsr + boff0[fg][s] + h * 32);
              acc[fg][0] = __builtin_amdgcn_mfma_f32_32x32x16_bf16(Aa, B, acc[fg][0], 0, 0, 0);
              acc[fg][1] = __builtin_amdgcn_mfma_f32_32x32x16_bf16(Ab, B, acc[fg][1], 0, 0, 0);
            }
          }
        }
      }
    }
    if (wid == 0) {
#pragma unroll
      for (int h = 0; h < 2; ++h) {
        const int ah = aoff1 + (h ? hstepA : 0);
        const bf16x8 Aa = *(const bf16x8*)(Asr + ah);
        const bf16x8 Ab = *(const bf16x8*)(Asr + ah + AB_OFF);
        const bf16x8 B = *(const bf16x8*)(xsr + boffW0 + h * 32);
        acc[2][0] = __builtin_amdgcn_mfma_f32_32x32x16_bf16(Aa, B, acc[2][0], 0, 0, 0);
        acc[2][1] = __builtin_amdgcn_mfma_f32_32x32x16_bf16(Ab, B, acc[2][1], 0, 0, 0);
      }
    }
    if (wid == 2) {
#pragma unroll
      for (int h = 0; h < 2; ++h) {
        const int ah = aoff1 + (h ? hstepA : 0);
        const bf16x8 Aa = *(const bf16x8*)(Asr + ah);
        const bf16x8 Ab = *(const bf16x8*)(Asr + ah + AB_OFF);
#pragma unroll
        for (int j = 0; j < 2; ++j) {
          const bf16x8 B = *(const bf16x8*)(xsr + boff1[j] + h * 32);
          acc[1 + j][0] = __builtin_amdgcn_mfma_f32_32x32x16_bf16(Aa, B, acc[1 + j][0], 0, 0, 0);
          acc[1 + j][1] = __builtin_amdgcn_mfma_f32_32x32x16_bf16(Ab, B, acc[1 + j][1], 0, 0, 0);
        }
      }
    }
    __builtin_amdgcn_s_setprio(0);

    if (have) {
      // x writes (verbatim R18)
#pragma unroll
      for (int t = 0; t < 4; ++t) {
        if (uact_[t]) {
          if (uint_[t]) {
#pragma unroll
            for (int e = 0; e < 4; ++e)
              *(short*)(xsw + uwb0_[t] + e * XS_STRIDE) = f2bf(xv[t][e]);
          } else {
#pragma unroll
            for (int e = 0; e < 4; ++e) {
              const int ww = 4 * uf4g_[t] + e - 3;
              if (ww >= 0 && ww < 18)
                *(short*)(xsw + (urow_[t] * 18 + ww) * XS_STRIDE + uic_[t] * 2) = f2bf(xv[t][e]);
            }
          }
        }
      }
      // w writes: incremental kq-walk, precomputed wrap position
#pragma unroll
      for (int k = 0; k < 9; ++k) {
        int a = woff0[k];
        const int wp = (int)((wpack >> (2 * k)) & 3u);
#pragma unroll
        for (int e = 0; e < 4; ++e) {
          *(short*)(Asw + a) = f2bf(wv[k][e]);
          a += (e == wp) ? wdelta[k] : KQ_PLANE;
        }
      }
    }
    __syncthreads();
  }

  // ---------------- epilogue: 2 phases (mf = oc-half), verbatim R18 ----------------
  short* hl = (short*)smem;
  const float kf4[4] = {0.25f, 0.75f, 0.75f, 0.25f};
#pragma unroll
  for (int mf = 0; mf < 2; ++mf) {
    if (mf) __syncthreads();
#pragma unroll
    for (int fg = 0; fg < 3; ++fg) {
      if (fg < nfg0 && valid0[fg]) {
#pragma unroll
        for (int e = 0; e < 16; ++e) {
          const int ocl = (e & 3) + 8 * (e >> 2) + 4 * q;
          hl[hbase0[fg] + ocl * 200] = f2bf(acc[fg][mf][e]);
        }
      }
    }
    if (wid == 0) {
#pragma unroll
      for (int e = 0; e < 16; ++e) {
        const int ocl = (e & 3) + 8 * (e >> 2) + 4 * q;
        hl[hbaseW0 + ocl * 200] = f2bf(acc[2][mf][e]);
      }
    }
    if (wid == 2) {
#pragma unroll
      for (int j = 0; j < 2; ++j) {
        if (valid1[j]) {
#pragma unroll
          for (int e = 0; e < 16; ++e) {
            const int ocl = (e & 3) + 8 * (e >> 2) + 4 * q;
            hl[hbase1[j] + ocl * 200] = f2bf(acc[1 + j][mf][e]);
          }
        }
      }
    }
    __syncthreads();
#pragma unroll
    for (int k = 0; k < 4; ++k) {
      const int v = tid + k * 512;
      const int g = v & 3;
      const int Yl = (v >> 2) & 15;
      const int ocl = v >> 6;
      float o[8];
#pragma unroll
      for (int xx = 0; xx < 8; ++xx) o[xx] = 0.f;
#pragma unroll
      for (int du = 0; du < 4; ++du) {
        const int ttp = Yl - 1 + du;
        const int py = ttp & 1;
        const int r = py ? ((Yl + du) >> 1) : (ttp >> 1);
        const int baseE = (py * 2) * 6400 + ocl * 200 + r * 20 + 4 * g;
        const int baseO = (py * 2 + 1) * 6400 + ocl * 200 + r * 20 + 4 * g;
        const short4v e0 = *(const short4v*)(hl + baseE);
        const short4v e1 = *(const short4v*)(hl + baseE + 4);
        const short4v o0 = *(const short4v*)(hl + baseO);
        const short4v o1 = *(const short4v*)(hl + baseO + 4);
        float E[8], O[8];
#pragma unroll
        for (int i = 0; i < 4; ++i) {
          E[i] = bf2f(e0[i]); E[i + 4] = bf2f(e1[i]);
          O[i] = bf2f(o0[i]); O[i + 4] = bf2f(o1[i]);
        }
        float rx[8];
        rx[0] = 0.25f*O[0] + 0.75f*E[0] + 0.75f*O[1] + 0.25f*E[1];
        rx[1] = 0.25f*E[0] + 0.75f*O[1] + 0.75f*E[1] + 0.25f*O[2];
        rx[2] = 0.25f*O[1] + 0.75f*E[1] + 0.75f*O[2] + 0.25f*E[2];
        rx[3] = 0.25f*E[1] + 0.75f*O[2] + 0.75f*E[2] + 0.25f*O[3];
        rx[4] = 0.25f*O[2] + 0.75f*E[2] + 0.75f*O[3] + 0.25f*E[3];
        rx[5] = 0.25f*E[2] + 0.75f*O[3] + 0.75f*E[3] + 0.25f*O[4];
        rx[6] = 0.25f*O[3] + 0.75f*E[3] + 0.75f*O[4] + 0.25f*E[4];
        rx[7] = 0.25f*E[3] + 0.75f*O[4] + 0.75f*E[4] + 0.25f*O[5];
        const float ky = kf4[du];
#pragma unroll
        for (int xx = 0; xx < 8; ++xx) o[xx] += ky * rx[xx];
      }
      const int oc = octile * 64 + mf * 32 + ocl;
      const int Y = atile * 16 + Yl;
      const int X0 = btile * 32 + g * 8;
      float* op = out + (((size_t)(n * 256 + oc)) * 128 + Y) * 128 + X0;
      f32x4v v0, v1;
      v0[0] = o[0]; v0[1] = o[1]; v0[2] = o[2]; v0[3] = o[3];
      v1[0] = o[4]; v1[1] = o[5]; v1[2] = o[6]; v1[3] = o[7];
      *(f32x4v*)op = v0;
      *(f32x4v*)(op + 4) = v1;
    }
  }
}

extern "C" void kernel_launch(void* const* d_in, const int* in_sizes, int n_in,
                              void* d_out, int out_size, void* d_ws, size_t ws_size,
                              hipStream_t stream) {
  (void)in_sizes; (void)n_in; (void)out_size; (void)d_ws; (void)ws_size;
  const float* x = (const float*)d_in[0];
  const float* w = (const float*)d_in[1];
  float* out = (float*)d_out;
  // grid = 4 octiles x 4 n x 32 spatial = 512 blocks, 512 threads
  hipLaunchKernelGGL(fir_up_v19, dim3(512), dim3(512), 0, stream, x, w, out);
}

// Round 21
// 81.699 us; speedup vs baseline: 1.3362x; 1.3362x over previous
//
#include <hip/hip_runtime.h>
#include <hip/hip_bf16.h>

// FirUpsample R20 = R18 revert (81.6us proven) + register-neutral cleanups:
//  - R19 fully reverted (its gather/swizzle rewrite added ~28 live regs ->
//    spill: VGPR capped 128, WRITE 65->104MB, dur 109us. Lesson: any "fix"
//    adding >8 live regs to this kernel spills under the (512,2) cap).
//  - dead pk computation removed from w-write path (R18 leftover).
//  - MERGED single-phase epilogue: hl[4][64 ocl][10][20] = 102.4 KB (aliases
//    the K-loop dbufs in the existing 121KB smem); both mf halves written
//    before ONE barrier; FIR 8 units/thread. Saves 2 block barriers + one
//    hl round-trip setup. Zero K-loop register impact.
// Math (verified R5-R19, absmax 0.015625): h = dilated conv3x3 as 4 parity-
// plane GEMMs (10.3 G MAC); separable 4-tap FIR epilogue from LDS.

typedef short bf16x4v __attribute__((ext_vector_type(4)));
typedef short bf16x8 __attribute__((ext_vector_type(8)));
typedef short short4v __attribute__((ext_vector_type(4)));
typedef float f32x16 __attribute__((ext_vector_type(16)));
typedef float f32x4v __attribute__((ext_vector_type(4)));

static __device__ __forceinline__ short f2bf(float f) {
  __hip_bfloat16 h = __float2bfloat16(f);
  union { __hip_bfloat16 h; short s; } u; u.h = h;
  return u.s;
}
static __device__ __forceinline__ float bf2f(short s) {
  union { unsigned u; float f; } v; v.u = ((unsigned)(unsigned short)s) << 16;
  return v.f;
}

#define AS_SZ 46080       // one As buffer: [9 kq][64 oc][80 B] (32 ic + 16B pad)
#define KQ_PLANE 5120     // 64 oc * 80 B
#define AB_OFF 2560       // +32 oc rows
#define XS_BASE 92160     // 2*AS_SZ
#define XS_SZ 14400       // one xs buffer: [180 cells][80 B]
#define XS_STRIDE 80

__global__ __launch_bounds__(512, 2)
void fir_up_v20(const float* __restrict__ x, const float* __restrict__ w,
                float* __restrict__ out) {
  __shared__ __align__(16) char smem[120960];

  const int bid = blockIdx.x;
  const int wg = (bid & 7) * 64 + (bid >> 3);
  const int octile = wg >> 7;        // 0..3 (64 oc each)
  const int n = (wg >> 5) & 3;
  const int sp = wg & 31;
  const int atile = sp >> 2;
  const int btile = sp & 3;
  const int A0 = atile * 8, B0 = btile * 16;

  const int tid = threadIdx.x;
  const int wid = tid >> 6;
  const int lane = tid & 63;
  const int l31 = lane & 31, q = lane >> 5;

  // ---- plane geometry + plane-grouped partition (R17/R18-verified) ----
  const int COLSt[4]  = {17, 18, 17, 18};
  const int CELLSt[4] = {153, 162, 170, 180};
  const int NKt[4]    = {4, 2, 2, 1};
  const int KQt[4][4] = {{0,2,6,8},{1,7,7,7},{3,5,5,5},{4,4,4,4}};
  const int DYt[4][4] = {{0,0,1,1},{0,1,1,1},{0,0,0,0},{0,0,0,0}};
  const int DXt[4][4] = {{0,1,0,1},{0,0,0,0},{0,1,1,1},{0,0,0,0}};
  // seg0: w0 p0{0,1} w1 p0{2,3} w2 p0{4} w3 p1{0,1,2} w4 p1{3,4,5}
  //       w5 p2{0,1,2} w6 p2{3,4,5} w7 p3{0,1,2}
  // seg1 (hardcoded): w0 += p3{3} -> acc[2];  w2 += p3{4,5} -> acc[1],acc[2]
  const int SEG0P[8]   = {0,0,0,1,1,2,2,3};
  const int SEG0FGB[8] = {0,2,4,0,3,0,3,0};
  const int SEG0NFG[8] = {2,2,1,3,3,3,3,3};

  const int p0w = SEG0P[wid];
  const int nk0 = NKt[p0w];
  const int nfg0 = SEG0NFG[wid];
  int aoff0[4];
#pragma unroll
  for (int s = 0; s < 4; ++s)
    aoff0[s] = KQt[p0w][s] * KQ_PLANE + l31 * 80 + q * 16;
  int boff0[3][4], valid0[3], hbase0[3];
#pragma unroll
  for (int fg = 0; fg < 3; ++fg) {
    const int cellraw = (SEG0FGB[wid] + fg) * 32 + l31;
    const int valid = cellraw < CELLSt[p0w];
    const int cell = valid ? cellraw : 0;
    const int cols = COLSt[p0w];
    const int r = cell / cols;
    const int c = cell - r * cols;
    valid0[fg] = valid;
    hbase0[fg] = p0w * 12800 + r * 20 + c;    // hl: plane 12800, ocl 200 (shorts)
#pragma unroll
    for (int s = 0; s < 4; ++s) {
      const int bc = (r + DYt[p0w][s]) * 18 + (c + DXt[p0w][s]);
      boff0[fg][s] = bc * XS_STRIDE + q * 16;
    }
  }
  // seg1 geometry (p3: kq=4, dy=dx=0)
  const int aoff1 = 4 * KQ_PLANE + l31 * 80 + q * 16;
  int boffW0, hbaseW0;
  {
    const int cell = 96 + l31;
    const int r = cell / 18, c = cell - r * 18;
    hbaseW0 = 3 * 12800 + r * 20 + c;
    boffW0 = cell * XS_STRIDE + q * 16;
  }
  int boff1[2], valid1[2], hbase1[2];
#pragma unroll
  for (int j = 0; j < 2; ++j) {
    const int cellraw = (4 + j) * 32 + l31;
    const int valid = cellraw < 180;
    const int cell = valid ? cellraw : 0;
    const int r = cell / 18, c = cell - r * 18;
    valid1[j] = valid;
    hbase1[j] = 3 * 12800 + r * 20 + c;
    boff1[j] = cell * XS_STRIDE + q * 16;
  }

  f32x16 acc[3][2];
#pragma unroll
  for (int fg = 0; fg < 3; ++fg)
#pragma unroll
    for (int mf = 0; mf < 2; ++mf)
#pragma unroll
      for (int e = 0; e < 16; ++e) acc[fg][mf][e] = 0.f;

  // ---- staging unit decode (verbatim R18) ----
  // A: unit = (ocA 0..63, icq 0..7): 36 consecutive floats = 4 ic x 9 kq
  const int ocA = tid >> 3, icq = tid & 7;
  const float* wA = w + (size_t)(octile * 64 + ocA) * 2304 + icq * 36;
  const int awb = ocA * 80 + icq * 8;   // + kq*KQ_PLANE at write
  // x: 1920 units, u = ic*60 + row*6 + f4g (f4g lane-minor, coalesced)
  int uic_[4], urow_[4], uf4g_[4], ugh_[4], ugw0_[4], uwb0_[4];
  bool uact_[4], urowok_[4], ual_[4], uint_[4];
#pragma unroll
  for (int t = 0; t < 4; ++t) {
    const int u = tid + t * 512;
    uact_[t] = u < 1920;
    const int uu = uact_[t] ? u : 0;
    uic_[t] = uu / 60;
    const int rem = uu - uic_[t] * 60;
    urow_[t] = rem / 6;
    uf4g_[t] = rem - urow_[t] * 6;
    ugh_[t] = A0 - 1 + urow_[t];
    urowok_[t] = (ugh_[t] >= 0) & (ugh_[t] < 64);
    ugw0_[t] = B0 - 4 + 4 * uf4g_[t];
    ual_[t] = (ugw0_[t] >= 0) & (ugw0_[t] <= 60);
    uint_[t] = (uf4g_[t] >= 1) & (uf4g_[t] <= 4);
    uwb0_[t] = (urow_[t] * 18 + (4 * uf4g_[t] - 3)) * XS_STRIDE + uic_[t] * 2;
  }

  // ---- prologue: stage chunk 0 into buffers 0 ----
  {
    char* xsw = smem + XS_BASE;
#pragma unroll
    for (int t = 0; t < 4; ++t) {
      if (uact_[t]) {
        float v[4] = {0.f, 0.f, 0.f, 0.f};
        if (urowok_[t]) {
          const float* base = x + (((size_t)(n * 256 + uic_[t])) * 64 + ugh_[t]) * 64;
          if (ual_[t]) {
            const f32x4v fv = *(const f32x4v*)(base + ugw0_[t]);
#pragma unroll
            for (int e = 0; e < 4; ++e) v[e] = fv[e];
          } else {
#pragma unroll
            for (int e = 0; e < 4; ++e) {
              const int gw = ugw0_[t] + e;
              v[e] = (gw >= 0 && gw < 64) ? base[gw] : 0.f;
            }
          }
        }
        if (uint_[t]) {
#pragma unroll
          for (int e = 0; e < 4; ++e)
            *(short*)(xsw + uwb0_[t] + e * XS_STRIDE) = f2bf(v[e]);
        } else {
#pragma unroll
          for (int e = 0; e < 4; ++e) {
            const int ww = 4 * uf4g_[t] + e - 3;
            if (ww >= 0 && ww < 18)
              *(short*)(xsw + (urow_[t] * 18 + ww) * XS_STRIDE + uic_[t] * 2) = f2bf(v[e]);
          }
        }
      }
    }
    float f36[36];
#pragma unroll
    for (int j = 0; j < 9; ++j)
      *(f32x4v*)&f36[4 * j] = *(const f32x4v*)(wA + 4 * j);
#pragma unroll
    for (int kq = 0; kq < 9; ++kq) {
      bf16x4v pk;
#pragma unroll
      for (int v = 0; v < 4; ++v) pk[v] = f2bf(f36[v * 9 + kq]);
      *(bf16x4v*)(smem + kq * KQ_PLANE + awb) = pk;
    }
  }
  __syncthreads();

  // ---------------- K-loop: 8 chunks of 32 ic, ONE barrier each ----------------
  for (int cc = 0; cc < 8; ++cc) {
    char* Asr = smem + (cc & 1) * AS_SZ;
    char* xsr = smem + XS_BASE + (cc & 1) * XS_SZ;
    char* Asw = smem + ((cc + 1) & 1) * AS_SZ;
    char* xsw = smem + XS_BASE + ((cc + 1) & 1) * XS_SZ;
    const bool have = cc < 7;

    // issue x loads for chunk cc+1 (latency hides under MFMA)
    float xv[4][4];
#pragma unroll
    for (int t = 0; t < 4; ++t) {
#pragma unroll
      for (int e = 0; e < 4; ++e) xv[t][e] = 0.f;
      if (have && uact_[t] && urowok_[t]) {
        const float* base =
            x + (((size_t)(n * 256 + (cc + 1) * 32 + uic_[t])) * 64 + ugh_[t]) * 64;
        if (ual_[t]) {
          const f32x4v fv = *(const f32x4v*)(base + ugw0_[t]);
#pragma unroll
          for (int e = 0; e < 4; ++e) xv[t][e] = fv[e];
        } else {
#pragma unroll
          for (int e = 0; e < 4; ++e) {
            const int gw = ugw0_[t] + e;
            xv[t][e] = (gw >= 0 && gw < 64) ? base[gw] : 0.f;
          }
        }
      }
    }
    // issue w loads for chunk cc+1 (L2-resident)
    f32x4v wv[9];
#pragma unroll
    for (int j = 0; j < 9; ++j) {
      if (have) wv[j] = *(const f32x4v*)(wA + (cc + 1) * 288 + 4 * j);
    }

    // MFMA on chunk cc: plane-grouped, 2 ic-halves per kq, prioritized
    __builtin_amdgcn_s_setprio(1);
#pragma unroll
    for (int s = 0; s < 4; ++s) {
      if (s < nk0) {
#pragma unroll
        for (int h = 0; h < 2; ++h) {
          const bf16x8 Aa = *(const bf16x8*)(Asr + aoff0[s] + h * 32);
          const bf16x8 Ab = *(const bf16x8*)(Asr + aoff0[s] + h * 32 + AB_OFF);
#pragma unroll
          for (int fg = 0; fg < 3; ++fg) {
            if (fg < nfg0) {
              const bf16x8 B = *(const bf16x8*)(xsr + boff0[fg][s] + h * 32);
              acc[fg][0] = __builtin_amdgcn_mfma_f32_32x32x16_bf16(Aa, B, acc[fg][0], 0, 0, 0);
              acc[fg][1] = __builtin_amdgcn_mfma_f32_32x32x16_bf16(Ab, B, acc[fg][1], 0, 0, 0);
            }
          }
        }
      }
    }
    if (wid == 0) {
#pragma unroll
      for (int h = 0; h < 2; ++h) {
        const bf16x8 Aa = *(const bf16x8*)(Asr + aoff1 + h * 32);
        const bf16x8 Ab = *(const bf16x8*)(Asr + aoff1 + h * 32 + AB_OFF);
        const bf16x8 B = *(const bf16x8*)(xsr + boffW0 + h * 32);
        acc[2][0] = __builtin_amdgcn_mfma_f32_32x32x16_bf16(Aa, B, acc[2][0], 0, 0, 0);
        acc[2][1] = __builtin_amdgcn_mfma_f32_32x32x16_bf16(Ab, B, acc[2][1], 0, 0, 0);
      }
    }
    if (wid == 2) {
#pragma unroll
      for (int h = 0; h < 2; ++h) {
        const bf16x8 Aa = *(const bf16x8*)(Asr + aoff1 + h * 32);
        const bf16x8 Ab = *(const bf16x8*)(Asr + aoff1 + h * 32 + AB_OFF);
#pragma unroll
        for (int j = 0; j < 2; ++j) {
          const bf16x8 B = *(const bf16x8*)(xsr + boff1[j] + h * 32);
          acc[1 + j][0] = __builtin_amdgcn_mfma_f32_32x32x16_bf16(Aa, B, acc[1 + j][0], 0, 0, 0);
          acc[1 + j][1] = __builtin_amdgcn_mfma_f32_32x32x16_bf16(Ab, B, acc[1 + j][1], 0, 0, 0);
        }
      }
    }
    __builtin_amdgcn_s_setprio(0);

    if (have) {
      // x writes
#pragma unroll
      for (int t = 0; t < 4; ++t) {
        if (uact_[t]) {
          if (uint_[t]) {
#pragma unroll
            for (int e = 0; e < 4; ++e)
              *(short*)(xsw + uwb0_[t] + e * XS_STRIDE) = f2bf(xv[t][e]);
          } else {
#pragma unroll
            for (int e = 0; e < 4; ++e) {
              const int ww = 4 * uf4g_[t] + e - 3;
              if (ww >= 0 && ww < 18)
                *(short*)(xsw + (urow_[t] * 18 + ww) * XS_STRIDE + uic_[t] * 2) = f2bf(xv[t][e]);
            }
          }
        }
      }
      // w writes (cleaned: direct indexing only)
#pragma unroll
      for (int kq = 0; kq < 9; ++kq) {
        bf16x4v pk;
#pragma unroll
        for (int v = 0; v < 4; ++v) {
          const int flat = v * 9 + kq;        // float index within 36
          pk[v] = f2bf(wv[flat >> 2][flat & 3]);
        }
        *(bf16x4v*)(Asw + kq * KQ_PLANE + awb) = pk;
      }
    }
    __syncthreads();
  }

  // ---------------- merged epilogue: ONE phase, hl[4][64][10][20] ----------------
  short* hl = (short*)smem;
  const float kf4[4] = {0.25f, 0.75f, 0.75f, 0.25f};
  // h-write: both mf halves; ocl = (e&3)+8*(e>>2)+4q + 32*mf
#pragma unroll
  for (int fg = 0; fg < 3; ++fg) {
    if (fg < nfg0 && valid0[fg]) {
#pragma unroll
      for (int mf = 0; mf < 2; ++mf)
#pragma unroll
        for (int e = 0; e < 16; ++e) {
          const int ocl = (e & 3) + 8 * (e >> 2) + 4 * q + 32 * mf;
          hl[hbase0[fg] + ocl * 200] = f2bf(acc[fg][mf][e]);
        }
    }
  }
  if (wid == 0) {
#pragma unroll
    for (int mf = 0; mf < 2; ++mf)
#pragma unroll
      for (int e = 0; e < 16; ++e) {
        const int ocl = (e & 3) + 8 * (e >> 2) + 4 * q + 32 * mf;
        hl[hbaseW0 + ocl * 200] = f2bf(acc[2][mf][e]);
      }
  }
  if (wid == 2) {
#pragma unroll
    for (int j = 0; j < 2; ++j) {
      if (valid1[j]) {
#pragma unroll
        for (int mf = 0; mf < 2; ++mf)
#pragma unroll
          for (int e = 0; e < 16; ++e) {
            const int ocl = (e & 3) + 8 * (e >> 2) + 4 * q + 32 * mf;
            hl[hbase1[j] + ocl * 200] = f2bf(acc[1 + j][mf][e]);
          }
      }
    }
  }
  __syncthreads();
  // FIR: 4096 units (64 ocl x 16 Yl x 4 g), 8 per thread; coalesced out writes
#pragma unroll
  for (int k = 0; k < 8; ++k) {
    const int v = tid + k * 512;
    const int g = v & 3;
    const int Yl = (v >> 2) & 15;
    const int ocl = v >> 6;           // 0..63
    float o[8];
#pragma unroll
    for (int xx = 0; xx < 8; ++xx) o[xx] = 0.f;
#pragma unroll
    for (int du = 0; du < 4; ++du) {
      const int ttp = Yl - 1 + du;
      const int py = ttp & 1;
      const int r = py ? ((Yl + du) >> 1) : (ttp >> 1);
      const int baseE = (py * 2) * 12800 + ocl * 200 + r * 20 + 4 * g;
      const int baseO = baseE + 12800;
      const short4v e0 = *(const short4v*)(hl + baseE);
      const short4v e1 = *(const short4v*)(hl + baseE + 4);
      const short4v o0 = *(const short4v*)(hl + baseO);
      const short4v o1 = *(const short4v*)(hl + baseO + 4);
      float E[8], O[8];
#pragma unroll
      for (int i = 0; i < 4; ++i) {
        E[i] = bf2f(e0[i]); E[i + 4] = bf2f(e1[i]);
        O[i] = bf2f(o0[i]); O[i + 4] = bf2f(o1[i]);
      }
      float rx[8];
      rx[0] = 0.25f*O[0] + 0.75f*E[0] + 0.75f*O[1] + 0.25f*E[1];
      rx[1] = 0.25f*E[0] + 0.75f*O[1] + 0.75f*E[1] + 0.25f*O[2];
      rx[2] = 0.25f*O[1] + 0.75f*E[1] + 0.75f*O[2] + 0.25f*E[2];
      rx[3] = 0.25f*E[1] + 0.75f*O[2] + 0.75f*E[2] + 0.25f*O[3];
      rx[4] = 0.25f*O[2] + 0.75f*E[2] + 0.75f*O[3] + 0.25f*E[3];
      rx[5] = 0.25f*E[2] + 0.75f*O[3] + 0.75f*E[3] + 0.25f*O[4];
      rx[6] = 0.25f*O[3] + 0.75f*E[3] + 0.75f*O[4] + 0.25f*E[4];
      rx[7] = 0.25f*E[3] + 0.75f*O[4] + 0.75f*E[4] + 0.25f*O[5];
      const float ky = kf4[du];
#pragma unroll
      for (int xx = 0; xx < 8; ++xx) o[xx] += ky * rx[xx];
    }
    const int oc = octile * 64 + ocl;
    const int Y = atile * 16 + Yl;
    const int X0 = btile * 32 + g * 8;
    float* op = out + (((size_t)(n * 256 + oc)) * 128 + Y) * 128 + X0;
    f32x4v v0, v1;
    v0[0] = o[0]; v0[1] = o[1]; v0[2] = o[2]; v0[3] = o[3];
    v1[0] = o[4]; v1[1] = o[5]; v1[2] = o[6]; v1[3] = o[7];
    *(f32x4v*)op = v0;
    *(f32x4v*)(op + 4) = v1;
  }
}

extern "C" void kernel_launch(void* const* d_in, const int* in_sizes, int n_in,
                              void* d_out, int out_size, void* d_ws, size_t ws_size,
                              hipStream_t stream) {
  (void)in_sizes; (void)n_in; (void)out_size; (void)d_ws; (void)ws_size;
  const float* x = (const float*)d_in[0];
  const float* w = (const float*)d_in[1];
  float* out = (float*)d_out;
  // grid = 4 octiles x 4 n x 32 spatial = 512 blocks, 512 threads
  hipLaunchKernelGGL(fir_up_v20, dim3(512), dim3(512), 0, stream, x, w, out);
}

// Round 22
// 73.646 us; speedup vs baseline: 1.4823x; 1.1093x over previous
//
#include <hip/hip_runtime.h>
#include <hip/hip_bf16.h>

// FirUpsample R21 = R20 (81.7us) + two register-audited staging fixes:
//  (1) ic-PAIRED x-stage: unit (icp,row,f4g) loads 2 f4s (ic,ic+1, 16KB apart)
//      and writes 4x ds_write_b32 (packed short2) -- x-write instrs halve
//      (16->8/thread/chunk), unit decode/guard VALU halves; loads unchanged.
//  (2) 2-deep x prefetch: k-loop unrolled x2 with NAMED xvA/xvB register sets
//      (no runtime indexing -> no scratch); loads for cc+2 issue at cc, so the
//      wait lands a full chunk (~900cyc) later -- x L3 latency fully hidden.
//      +16 held VGPR: ~140+96 AGPR = 236 <= 256, no spill (R19 failed at 248).
// w-path / MFMA partition / barriers / setprio / merged epilogue = R20.
// Math (verified R5-R20, absmax 0.015625): h = dilated conv3x3 as 4 parity-
// plane GEMMs (10.3 G MAC); separable 4-tap FIR epilogue from LDS.

typedef short bf16x4v __attribute__((ext_vector_type(4)));
typedef short bf16x8 __attribute__((ext_vector_type(8)));
typedef short short4v __attribute__((ext_vector_type(4)));
typedef float f32x16 __attribute__((ext_vector_type(16)));
typedef float f32x4v __attribute__((ext_vector_type(4)));

static __device__ __forceinline__ short f2bf(float f) {
  __hip_bfloat16 h = __float2bfloat16(f);
  union { __hip_bfloat16 h; short s; } u; u.h = h;
  return u.s;
}
static __device__ __forceinline__ float bf2f(short s) {
  union { unsigned u; float f; } v; v.u = ((unsigned)(unsigned short)s) << 16;
  return v.f;
}
static __device__ __forceinline__ int pack2(float a, float b) {
  return ((int)(unsigned short)f2bf(a)) | (((int)(unsigned short)f2bf(b)) << 16);
}

#define AS_SZ 46080       // one As buffer: [9 kq][64 oc][80 B] (32 ic + 16B pad)
#define KQ_PLANE 5120     // 64 oc * 80 B
#define AB_OFF 2560       // +32 oc rows
#define XS_BASE 92160     // 2*AS_SZ
#define XS_SZ 14400       // one xs buffer: [180 cells][80 B]
#define XS_STRIDE 80

__global__ __launch_bounds__(512, 2)
void fir_up_v21(const float* __restrict__ x, const float* __restrict__ w,
                float* __restrict__ out) {
  __shared__ __align__(16) char smem[120960];

  const int bid = blockIdx.x;
  const int wg = (bid & 7) * 64 + (bid >> 3);
  const int octile = wg >> 7;        // 0..3 (64 oc each)
  const int n = (wg >> 5) & 3;
  const int sp = wg & 31;
  const int atile = sp >> 2;
  const int btile = sp & 3;
  const int A0 = atile * 8, B0 = btile * 16;

  const int tid = threadIdx.x;
  const int wid = tid >> 6;
  const int lane = tid & 63;
  const int l31 = lane & 31, q = lane >> 5;

  // ---- plane geometry + plane-grouped partition (R17-R20 verified) ----
  const int COLSt[4]  = {17, 18, 17, 18};
  const int CELLSt[4] = {153, 162, 170, 180};
  const int NKt[4]    = {4, 2, 2, 1};
  const int KQt[4][4] = {{0,2,6,8},{1,7,7,7},{3,5,5,5},{4,4,4,4}};
  const int DYt[4][4] = {{0,0,1,1},{0,1,1,1},{0,0,0,0},{0,0,0,0}};
  const int DXt[4][4] = {{0,1,0,1},{0,0,0,0},{0,1,1,1},{0,0,0,0}};
  const int SEG0P[8]   = {0,0,0,1,1,2,2,3};
  const int SEG0FGB[8] = {0,2,4,0,3,0,3,0};
  const int SEG0NFG[8] = {2,2,1,3,3,3,3,3};

  const int p0w = SEG0P[wid];
  const int nk0 = NKt[p0w];
  const int nfg0 = SEG0NFG[wid];
  int aoff0[4];
#pragma unroll
  for (int s = 0; s < 4; ++s)
    aoff0[s] = KQt[p0w][s] * KQ_PLANE + l31 * 80 + q * 16;
  int boff0[3][4], valid0[3], hbase0[3];
#pragma unroll
  for (int fg = 0; fg < 3; ++fg) {
    const int cellraw = (SEG0FGB[wid] + fg) * 32 + l31;
    const int valid = cellraw < CELLSt[p0w];
    const int cell = valid ? cellraw : 0;
    const int cols = COLSt[p0w];
    const int r = cell / cols;
    const int c = cell - r * cols;
    valid0[fg] = valid;
    hbase0[fg] = p0w * 12800 + r * 20 + c;    // hl: plane 12800, ocl 200 (shorts)
#pragma unroll
    for (int s = 0; s < 4; ++s) {
      const int bc = (r + DYt[p0w][s]) * 18 + (c + DXt[p0w][s]);
      boff0[fg][s] = bc * XS_STRIDE + q * 16;
    }
  }
  const int aoff1 = 4 * KQ_PLANE + l31 * 80 + q * 16;
  int boffW0, hbaseW0;
  {
    const int cell = 96 + l31;
    const int r = cell / 18, c = cell - r * 18;
    hbaseW0 = 3 * 12800 + r * 20 + c;
    boffW0 = cell * XS_STRIDE + q * 16;
  }
  int boff1[2], valid1[2], hbase1[2];
#pragma unroll
  for (int j = 0; j < 2; ++j) {
    const int cellraw = (4 + j) * 32 + l31;
    const int valid = cellraw < 180;
    const int cell = valid ? cellraw : 0;
    const int r = cell / 18, c = cell - r * 18;
    valid1[j] = valid;
    hbase1[j] = 3 * 12800 + r * 20 + c;
    boff1[j] = cell * XS_STRIDE + q * 16;
  }

  f32x16 acc[3][2];
#pragma unroll
  for (int fg = 0; fg < 3; ++fg)
#pragma unroll
    for (int mf = 0; mf < 2; ++mf)
#pragma unroll
      for (int e = 0; e < 16; ++e) acc[fg][mf][e] = 0.f;

  // ---- staging unit decode ----
  // A: unit = (ocA, icq): 36 consecutive floats = 4 ic x 9 kq (verbatim R20)
  const int ocA = tid >> 3, icq = tid & 7;
  const float* wA = w + (size_t)(octile * 64 + ocA) * 2304 + icq * 36;
  const int awb = ocA * 80 + icq * 8;
  // x: 960 ic-PAIRED units, u = icp*60 + row*6 + f4g (f4g lane-minor)
  int uicp_[2], urow_[2], uf4g_[2], ugh_[2], ugw0_[2], uwb0_[2];
  bool uact_[2], urowok_[2], ual_[2], uint_[2];
#pragma unroll
  for (int t = 0; t < 2; ++t) {
    const int u = tid + t * 512;
    uact_[t] = u < 960;
    const int uu = uact_[t] ? u : 0;
    uicp_[t] = uu / 60;
    const int rem = uu - uicp_[t] * 60;
    urow_[t] = rem / 6;
    uf4g_[t] = rem - urow_[t] * 6;
    ugh_[t] = A0 - 1 + urow_[t];
    urowok_[t] = (ugh_[t] >= 0) & (ugh_[t] < 64);
    ugw0_[t] = B0 - 4 + 4 * uf4g_[t];
    ual_[t] = (ugw0_[t] >= 0) & (ugw0_[t] <= 60);
    uint_[t] = (uf4g_[t] >= 1) & (uf4g_[t] <= 4);
    uwb0_[t] = (urow_[t] * 18 + (4 * uf4g_[t] - 3)) * XS_STRIDE + uicp_[t] * 4;
  }

// load both ics of each unit for chunk CH into xv[t][0..3]=icA, [t][4..7]=icB
#define LOAD_X(xv, CH)                                                         \
  {                                                                            \
    _Pragma("unroll") for (int t = 0; t < 2; ++t) {                            \
      _Pragma("unroll") for (int j = 0; j < 8; ++j) xv[t][j] = 0.f;            \
      if (uact_[t] && urowok_[t]) {                                            \
        const float* baseA =                                                   \
            x + (((size_t)(n * 256 + (CH) * 32 + 2 * uicp_[t])) * 64 + ugh_[t]) * 64; \
        if (ual_[t]) {                                                         \
          const f32x4v fA = *(const f32x4v*)(baseA + ugw0_[t]);                \
          const f32x4v fB = *(const f32x4v*)(baseA + 4096 + ugw0_[t]);         \
          _Pragma("unroll") for (int e = 0; e < 4; ++e) {                      \
            xv[t][e] = fA[e]; xv[t][4 + e] = fB[e];                            \
          }                                                                    \
        } else {                                                               \
          _Pragma("unroll") for (int e = 0; e < 4; ++e) {                      \
            const int gw = ugw0_[t] + e;                                       \
            const bool ok = (gw >= 0) & (gw < 64);                             \
            xv[t][e] = ok ? baseA[gw] : 0.f;                                   \
            xv[t][4 + e] = ok ? baseA[4096 + gw] : 0.f;                        \
          }                                                                    \
        }                                                                      \
      }                                                                        \
    }                                                                          \
  }

// write xv to xs buffer XSW (4x b32 packed per unit)
#define WRITE_X(XSW, xv)                                                       \
  {                                                                            \
    _Pragma("unroll") for (int t = 0; t < 2; ++t) {                            \
      if (uact_[t]) {                                                          \
        if (uint_[t]) {                                                        \
          _Pragma("unroll") for (int e = 0; e < 4; ++e)                        \
            *(int*)((XSW) + uwb0_[t] + e * XS_STRIDE) =                        \
                pack2(xv[t][e], xv[t][4 + e]);                                 \
        } else {                                                               \
          _Pragma("unroll") for (int e = 0; e < 4; ++e) {                      \
            const int ww = 4 * uf4g_[t] + e - 3;                               \
            if (ww >= 0 && ww < 18)                                            \
              *(int*)((XSW) + (urow_[t] * 18 + ww) * XS_STRIDE + uicp_[t] * 4) = \
                  pack2(xv[t][e], xv[t][4 + e]);                               \
          }                                                                    \
        }                                                                      \
      }                                                                        \
    }                                                                          \
  }

// MFMA cluster on buffers (ASR, XSR) -- verbatim R20 partition
#define MFMA_CHUNK(ASR, XSR)                                                   \
  {                                                                            \
    __builtin_amdgcn_s_setprio(1);                                             \
    _Pragma("unroll") for (int s = 0; s < 4; ++s) {                            \
      if (s < nk0) {                                                           \
        _Pragma("unroll") for (int h = 0; h < 2; ++h) {                        \
          const bf16x8 Aa = *(const bf16x8*)((ASR) + aoff0[s] + h * 32);       \
          const bf16x8 Ab = *(const bf16x8*)((ASR) + aoff0[s] + h * 32 + AB_OFF); \
          _Pragma("unroll") for (int fg = 0; fg < 3; ++fg) {                   \
            if (fg < nfg0) {                                                   \
              const bf16x8 B = *(const bf16x8*)((XSR) + boff0[fg][s] + h * 32);\
              acc[fg][0] = __builtin_amdgcn_mfma_f32_32x32x16_bf16(Aa, B, acc[fg][0], 0, 0, 0); \
              acc[fg][1] = __builtin_amdgcn_mfma_f32_32x32x16_bf16(Ab, B, acc[fg][1], 0, 0, 0); \
            }                                                                  \
          }                                                                    \
        }                                                                      \
      }                                                                        \
    }                                                                          \
    if (wid == 0) {                                                            \
      _Pragma("unroll") for (int h = 0; h < 2; ++h) {                          \
        const bf16x8 Aa = *(const bf16x8*)((ASR) + aoff1 + h * 32);            \
        const bf16x8 Ab = *(const bf16x8*)((ASR) + aoff1 + h * 32 + AB_OFF);   \
        const bf16x8 B = *(const bf16x8*)((XSR) + boffW0 + h * 32);            \
        acc[2][0] = __builtin_amdgcn_mfma_f32_32x32x16_bf16(Aa, B, acc[2][0], 0, 0, 0); \
        acc[2][1] = __builtin_amdgcn_mfma_f32_32x32x16_bf16(Ab, B, acc[2][1], 0, 0, 0); \
      }                                                                        \
    }                                                                          \
    if (wid == 2) {                                                            \
      _Pragma("unroll") for (int h = 0; h < 2; ++h) {                          \
        const bf16x8 Aa = *(const bf16x8*)((ASR) + aoff1 + h * 32);            \
        const bf16x8 Ab = *(const bf16x8*)((ASR) + aoff1 + h * 32 + AB_OFF);   \
        _Pragma("unroll") for (int j = 0; j < 2; ++j) {                        \
          const bf16x8 B = *(const bf16x8*)((XSR) + boff1[j] + h * 32);        \
          acc[1 + j][0] = __builtin_amdgcn_mfma_f32_32x32x16_bf16(Aa, B, acc[1 + j][0], 0, 0, 0); \
          acc[1 + j][1] = __builtin_amdgcn_mfma_f32_32x32x16_bf16(Ab, B, acc[1 + j][1], 0, 0, 0); \
        }                                                                      \
      }                                                                        \
    }                                                                          \
    __builtin_amdgcn_s_setprio(0);                                             \
  }

// w stage for chunk CH into ASW (verbatim R20)
#define STAGE_W(ASW, CH)                                                       \
  {                                                                            \
    f32x4v wv[9];                                                              \
    _Pragma("unroll") for (int j = 0; j < 9; ++j)                              \
      wv[j] = *(const f32x4v*)(wA + (CH) * 288 + 4 * j);                       \
    _Pragma("unroll") for (int kq = 0; kq < 9; ++kq) {                         \
      bf16x4v pk;                                                              \
      _Pragma("unroll") for (int v = 0; v < 4; ++v) {                          \
        const int flat = v * 9 + kq;                                           \
        pk[v] = f2bf(wv[flat >> 2][flat & 3]);                                 \
      }                                                                        \
      *(bf16x4v*)((ASW) + kq * KQ_PLANE + awb) = pk;                           \
    }                                                                          \
  }

  float xvA[2][8], xvB[2][8];

  // ---- prologue: stage chunk 0 direct; issue xvA loads for chunk 1 ----
  {
    LOAD_X(xvB, 0);                       // chunk-0 data (transient)
    WRITE_X(smem + XS_BASE, xvB);
    STAGE_W(smem, 0);
    LOAD_X(xvA, 1);                       // 2-deep pipeline primer
  }
  __syncthreads();

  // ---------------- K-loop: 8 chunks (unrolled x2), ONE barrier each ----------------
  char* As0 = smem;
  char* As1 = smem + AS_SZ;
  char* xs0 = smem + XS_BASE;
  char* xs1 = smem + XS_BASE + XS_SZ;
  for (int ccp = 0; ccp < 4; ++ccp) {
    const int cc0 = 2 * ccp;              // even chunk: read buf0, write buf1
    {
      if (cc0 + 2 <= 7) LOAD_X(xvB, cc0 + 2);
      MFMA_CHUNK(As0, xs0);
      if (cc0 + 1 <= 7) {
        WRITE_X(xs1, xvA);
        STAGE_W(As1, cc0 + 1);
      }
      __syncthreads();
    }
    const int cc1 = cc0 + 1;              // odd chunk: read buf1, write buf0
    {
      if (cc1 + 2 <= 7) LOAD_X(xvA, cc1 + 2);
      MFMA_CHUNK(As1, xs1);
      if (cc1 + 1 <= 7) {
        WRITE_X(xs0, xvB);
        STAGE_W(As0, cc1 + 1);
      }
      __syncthreads();
    }
  }

  // ---------------- merged epilogue: ONE phase, hl[4][64][10][20] (R20) ----------------
  short* hl = (short*)smem;
  const float kf4[4] = {0.25f, 0.75f, 0.75f, 0.25f};
#pragma unroll
  for (int fg = 0; fg < 3; ++fg) {
    if (fg < nfg0 && valid0[fg]) {
#pragma unroll
      for (int mf = 0; mf < 2; ++mf)
#pragma unroll
        for (int e = 0; e < 16; ++e) {
          const int ocl = (e & 3) + 8 * (e >> 2) + 4 * q + 32 * mf;
          hl[hbase0[fg] + ocl * 200] = f2bf(acc[fg][mf][e]);
        }
    }
  }
  if (wid == 0) {
#pragma unroll
    for (int mf = 0; mf < 2; ++mf)
#pragma unroll
      for (int e = 0; e < 16; ++e) {
        const int ocl = (e & 3) + 8 * (e >> 2) + 4 * q + 32 * mf;
        hl[hbaseW0 + ocl * 200] = f2bf(acc[2][mf][e]);
      }
  }
  if (wid == 2) {
#pragma unroll
    for (int j = 0; j < 2; ++j) {
      if (valid1[j]) {
#pragma unroll
        for (int mf = 0; mf < 2; ++mf)
#pragma unroll
          for (int e = 0; e < 16; ++e) {
            const int ocl = (e & 3) + 8 * (e >> 2) + 4 * q + 32 * mf;
            hl[hbase1[j] + ocl * 200] = f2bf(acc[1 + j][mf][e]);
          }
      }
    }
  }
  __syncthreads();
#pragma unroll
  for (int k = 0; k < 8; ++k) {
    const int v = tid + k * 512;
    const int g = v & 3;
    const int Yl = (v >> 2) & 15;
    const int ocl = v >> 6;           // 0..63
    float o[8];
#pragma unroll
    for (int xx = 0; xx < 8; ++xx) o[xx] = 0.f;
#pragma unroll
    for (int du = 0; du < 4; ++du) {
      const int ttp = Yl - 1 + du;
      const int py = ttp & 1;
      const int r = py ? ((Yl + du) >> 1) : (ttp >> 1);
      const int baseE = (py * 2) * 12800 + ocl * 200 + r * 20 + 4 * g;
      const int baseO = baseE + 12800;
      const short4v e0 = *(const short4v*)(hl + baseE);
      const short4v e1 = *(const short4v*)(hl + baseE + 4);
      const short4v o0 = *(const short4v*)(hl + baseO);
      const short4v o1 = *(const short4v*)(hl + baseO + 4);
      float E[8], O[8];
#pragma unroll
      for (int i = 0; i < 4; ++i) {
        E[i] = bf2f(e0[i]); E[i + 4] = bf2f(e1[i]);
        O[i] = bf2f(o0[i]); O[i + 4] = bf2f(o1[i]);
      }
      float rx[8];
      rx[0] = 0.25f*O[0] + 0.75f*E[0] + 0.75f*O[1] + 0.25f*E[1];
      rx[1] = 0.25f*E[0] + 0.75f*O[1] + 0.75f*E[1] + 0.25f*O[2];
      rx[2] = 0.25f*O[1] + 0.75f*E[1] + 0.75f*O[2] + 0.25f*E[2];
      rx[3] = 0.25f*E[1] + 0.75f*O[2] + 0.75f*E[2] + 0.25f*O[3];
      rx[4] = 0.25f*O[2] + 0.75f*E[2] + 0.75f*O[3] + 0.25f*E[3];
      rx[5] = 0.25f*E[2] + 0.75f*O[3] + 0.75f*E[3] + 0.25f*O[4];
      rx[6] = 0.25f*O[3] + 0.75f*E[3] + 0.75f*O[4] + 0.25f*E[4];
      rx[7] = 0.25f*E[3] + 0.75f*O[4] + 0.75f*E[4] + 0.25f*O[5];
      const float ky = kf4[du];
#pragma unroll
      for (int xx = 0; xx < 8; ++xx) o[xx] += ky * rx[xx];
    }
    const int oc = octile * 64 + ocl;
    const int Y = atile * 16 + Yl;
    const int X0 = btile * 32 + g * 8;
    float* op = out + (((size_t)(n * 256 + oc)) * 128 + Y) * 128 + X0;
    f32x4v v0, v1;
    v0[0] = o[0]; v0[1] = o[1]; v0[2] = o[2]; v0[3] = o[3];
    v1[0] = o[4]; v1[1] = o[5]; v1[2] = o[6]; v1[3] = o[7];
    *(f32x4v*)op = v0;
    *(f32x4v*)(op + 4) = v1;
  }
}

extern "C" void kernel_launch(void* const* d_in, const int* in_sizes, int n_in,
                              void* d_out, int out_size, void* d_ws, size_t ws_size,
                              hipStream_t stream) {
  (void)in_sizes; (void)n_in; (void)out_size; (void)d_ws; (void)ws_size;
  const float* x = (const float*)d_in[0];
  const float* w = (const float*)d_in[1];
  float* out = (float*)d_out;
  // grid = 4 octiles x 4 n x 32 spatial = 512 blocks, 512 threads
  hipLaunchKernelGGL(fir_up_v21, dim3(512), dim3(512), 0, stream, x, w, out);
}